// Round 1
// baseline (1263.874 us; speedup 1.0000x reference)
//
#include <hip/hip_runtime.h>
#include <hip/hip_bf16.h>

// Problem constants (CausalSelfAttention, B=2, T=2048, C=1024, H=16, D=64)
#define BSZ 2
#define SEQ 2048
#define NEMBD 1024
#define NHEAD 16
#define HDIM 64
#define BT (BSZ * SEQ)          // 4096
#define QKV_LD (3 * NEMBD)      // 3072

// ---------------------------------------------------------------------------
// Tiled fp32 GEMM: C[M,N] = A[M,K] * B[N,K]^T   (all row-major)
// 64x64 tile, BK=16, 256 threads, 4x4 accum per thread.
// ---------------------------------------------------------------------------
__global__ __launch_bounds__(256) void gemm_nt(const float* __restrict__ A,
                                               const float* __restrict__ B,
                                               float* __restrict__ C,
                                               int M, int N, int K) {
    __shared__ float As[16][68];   // [k][m], pad 68 for store-bank spread + 16B align
    __shared__ float Bs[16][68];   // [k][n]
    const int tid = threadIdx.x;
    const int tx = tid & 15, ty = tid >> 4;
    const int m0 = blockIdx.y * 64, n0 = blockIdx.x * 64;

    const int lrow = tid >> 2;          // 0..63 (tile row)
    const int lkq  = (tid & 3) << 2;    // 0,4,8,12 (k offset)
    const float* Ap = A + (size_t)(m0 + lrow) * K + lkq;
    const float* Bp = B + (size_t)(n0 + lrow) * K + lkq;

    float acc[4][4] = {};

    for (int k0 = 0; k0 < K; k0 += 16) {
        float4 av = *(const float4*)(Ap + k0);
        float4 bv = *(const float4*)(Bp + k0);
        __syncthreads();  // previous iteration's readers done
        As[lkq + 0][lrow] = av.x; As[lkq + 1][lrow] = av.y;
        As[lkq + 2][lrow] = av.z; As[lkq + 3][lrow] = av.w;
        Bs[lkq + 0][lrow] = bv.x; Bs[lkq + 1][lrow] = bv.y;
        Bs[lkq + 2][lrow] = bv.z; Bs[lkq + 3][lrow] = bv.w;
        __syncthreads();
#pragma unroll
        for (int kk = 0; kk < 16; ++kk) {
            float a[4], b[4];
#pragma unroll
            for (int i = 0; i < 4; ++i) a[i] = As[kk][ty * 4 + i];
#pragma unroll
            for (int j = 0; j < 4; ++j) b[j] = Bs[kk][tx * 4 + j];
#pragma unroll
            for (int i = 0; i < 4; ++i)
#pragma unroll
                for (int j = 0; j < 4; ++j)
                    acc[i][j] = fmaf(a[i], b[j], acc[i][j]);
        }
    }

#pragma unroll
    for (int i = 0; i < 4; ++i) {
        float4 v = make_float4(acc[i][0], acc[i][1], acc[i][2], acc[i][3]);
        *(float4*)&C[(size_t)(m0 + ty * 4 + i) * N + n0 + tx * 4] = v;
    }
}

// ---------------------------------------------------------------------------
// Flash-attention fp32 forward (causal). One block per (head, 64-query tile).
// qkv layout: [BT, 3072] with q at col 0, k at col 1024, v at col 2048;
// head h occupies cols h*64..h*64+63 within each third.
// Writes y: [BT, 1024] (heads re-interleaved).
// ---------------------------------------------------------------------------
__global__ __launch_bounds__(256) void attn_fwd(const float* __restrict__ qkv,
                                                float* __restrict__ y) {
    const int bh = blockIdx.y;          // 0..31
    const int b  = bh >> 4, h = bh & 15;
    const int qt = blockIdx.x;          // 0..31 (64-row query tile)
    const int tid = threadIdx.x;
    const int tx = tid & 15, ty = tid >> 4;

    __shared__ float QsT[64][65];       // [d][qrow]
    __shared__ float KV[64 * 65];       // K as KT[d][krow] stride 65; later V[krow][d] stride 64
    __shared__ float Ss[64][65];        // scores / probabilities [qrow][krow]
    __shared__ float row_m[64], row_l[64], row_alpha[64];

    const float scale = 0.125f;         // 1/sqrt(64)

    const int lcol = tid >> 2;          // 0..63 (tile row index for loads)
    const int ldq  = (tid & 3) << 4;    // 0,16,32,48 (d chunk)

    // ---- load Q tile transposed ----
    {
        const float* qp = qkv + (size_t)(b * SEQ + qt * 64 + lcol) * QKV_LD + h * HDIM + ldq;
#pragma unroll
        for (int e4 = 0; e4 < 4; ++e4) {
            float4 v = *(const float4*)(qp + e4 * 4);
            QsT[ldq + e4 * 4 + 0][lcol] = v.x;
            QsT[ldq + e4 * 4 + 1][lcol] = v.y;
            QsT[ldq + e4 * 4 + 2][lcol] = v.z;
            QsT[ldq + e4 * 4 + 3][lcol] = v.w;
        }
    }
    if (tid < 64) { row_m[tid] = -1e30f; row_l[tid] = 0.0f; }

    float o[4][4] = {};

    for (int kt = 0; kt <= qt; ++kt) {
        __syncthreads();  // prev PV done / Q+state stores visible
        // ---- load K tile transposed into KV ----
        {
            const float* kp = qkv + (size_t)(b * SEQ + kt * 64 + lcol) * QKV_LD + NEMBD + h * HDIM + ldq;
#pragma unroll
            for (int e4 = 0; e4 < 4; ++e4) {
                float4 v = *(const float4*)(kp + e4 * 4);
                KV[(ldq + e4 * 4 + 0) * 65 + lcol] = v.x;
                KV[(ldq + e4 * 4 + 1) * 65 + lcol] = v.y;
                KV[(ldq + e4 * 4 + 2) * 65 + lcol] = v.z;
                KV[(ldq + e4 * 4 + 3) * 65 + lcol] = v.w;
            }
        }
        __syncthreads();
        // ---- S = scale * Q K^T (4x4 per thread) ----
        float s[4][4] = {};
#pragma unroll 4
        for (int d = 0; d < 64; ++d) {
            float a[4], k4[4];
#pragma unroll
            for (int i = 0; i < 4; ++i) a[i] = QsT[d][ty * 4 + i];
#pragma unroll
            for (int j = 0; j < 4; ++j) k4[j] = KV[d * 65 + tx * 4 + j];
#pragma unroll
            for (int i = 0; i < 4; ++i)
#pragma unroll
                for (int j = 0; j < 4; ++j)
                    s[i][j] = fmaf(a[i], k4[j], s[i][j]);
        }
#pragma unroll
        for (int i = 0; i < 4; ++i)
#pragma unroll
            for (int j = 0; j < 4; ++j) {
                float v = s[i][j] * scale;
                if (kt == qt && (tx * 4 + j) > (ty * 4 + i)) v = -1e30f;  // causal mask
                Ss[ty * 4 + i][tx * 4 + j] = v;
            }
        __syncthreads();
        // ---- load V tile (overwrites K region; safe: S is materialized) ----
        {
            const float* vp = qkv + (size_t)(b * SEQ + kt * 64 + lcol) * QKV_LD + 2 * NEMBD + h * HDIM + ldq;
#pragma unroll
            for (int e4 = 0; e4 < 4; ++e4) {
                float4 v = *(const float4*)(vp + e4 * 4);
                *(float4*)&KV[lcol * 64 + ldq + e4 * 4] = v;
            }
        }
        // ---- online softmax (wave 0; overlaps V load) ----
        if (tid < 64) {
            const int r = tid;
            float mx = row_m[r];
            float tmax = -1e30f;
#pragma unroll 8
            for (int c = 0; c < 64; ++c) tmax = fmaxf(tmax, Ss[r][c]);
            float nm = fmaxf(mx, tmax);
            float alpha = __expf(mx - nm);
            float sum = 0.0f;
#pragma unroll 8
            for (int c = 0; c < 64; ++c) {
                float p = __expf(Ss[r][c] - nm);
                Ss[r][c] = p;
                sum += p;
            }
            row_l[r] = row_l[r] * alpha + sum;
            row_m[r] = nm;
            row_alpha[r] = alpha;
        }
        __syncthreads();
        // ---- O = O*alpha + P @ V ----
#pragma unroll
        for (int i = 0; i < 4; ++i) {
            float al = row_alpha[ty * 4 + i];
#pragma unroll
            for (int j = 0; j < 4; ++j) o[i][j] *= al;
        }
#pragma unroll 4
        for (int jp = 0; jp < 64; ++jp) {
            float p[4], vv[4];
#pragma unroll
            for (int i = 0; i < 4; ++i) p[i] = Ss[ty * 4 + i][jp];
#pragma unroll
            for (int j = 0; j < 4; ++j) vv[j] = KV[jp * 64 + tx * 4 + j];
#pragma unroll
            for (int i = 0; i < 4; ++i)
#pragma unroll
                for (int j = 0; j < 4; ++j)
                    o[i][j] = fmaf(p[i], vv[j], o[i][j]);
        }
    }

    // ---- epilogue: normalize and store y ----
#pragma unroll
    for (int i = 0; i < 4; ++i) {
        const int qrow = ty * 4 + i;
        float inv = 1.0f / row_l[qrow];
        float4 v = make_float4(o[i][0] * inv, o[i][1] * inv, o[i][2] * inv, o[i][3] * inv);
        *(float4*)&y[(size_t)(b * SEQ + qt * 64 + qrow) * NEMBD + h * HDIM + tx * 4] = v;
    }
}

// ---------------------------------------------------------------------------
extern "C" void kernel_launch(void* const* d_in, const int* in_sizes, int n_in,
                              void* d_out, int out_size, void* d_ws, size_t ws_size,
                              hipStream_t stream) {
    const float* x      = (const float*)d_in[0];   // [2,2048,1024] fp32
    const float* w_attn = (const float*)d_in[1];   // [3072,1024]   fp32
    const float* w_proj = (const float*)d_in[2];   // [1024,1024]   fp32
    float* out = (float*)d_out;                    // [2,2048,1024] fp32

    float* qkv = (float*)d_ws;                         // BT*3072 fp32 = 50.3 MB
    float* yws = qkv + (size_t)BT * QKV_LD;            // BT*1024 fp32 = 16.8 MB

    // 1) qkv = x @ w_attn^T   [4096,1024]x[3072,1024]^T
    gemm_nt<<<dim3(QKV_LD / 64, BT / 64), 256, 0, stream>>>(x, w_attn, qkv, BT, QKV_LD, NEMBD);

    // 2) fused causal attention -> y [4096,1024]
    attn_fwd<<<dim3(SEQ / 64, BSZ * NHEAD), 256, 0, stream>>>(qkv, yws);

    // 3) out = y @ w_proj^T   [4096,1024]x[1024,1024]^T
    gemm_nt<<<dim3(NEMBD / 64, BT / 64), 256, 0, stream>>>(yws, w_proj, out, BT, NEMBD, NEMBD);
}

// Round 2
// 311.435 us; speedup vs baseline: 4.0582x; 4.0582x over previous
//
#include <hip/hip_runtime.h>

// CausalSelfAttention: B=2, T=2048, C=1024, H=16, D=64 — bf16 MFMA rewrite.
#define BSZ 2
#define SEQ 2048
#define NEMBD 1024
#define NHEAD 16
#define HDIM 64
#define BT (BSZ * SEQ)          // 4096
#define QKV_LD (3 * NEMBD)      // 3072
#define LOG2E 1.4426950408889634f

typedef unsigned short u16;
typedef __attribute__((ext_vector_type(8))) short short8;   // 8 bf16 = 4 VGPRs (MFMA A/B frag)
typedef __attribute__((ext_vector_type(4))) float floatx4;  // MFMA C/D frag

#define MFMA16(a, b, c) __builtin_amdgcn_mfma_f32_16x16x32_bf16(a, b, c, 0, 0, 0)

__device__ __forceinline__ void gload_lds16(const void* g, void* l) {
  __builtin_amdgcn_global_load_lds(
      (const __attribute__((address_space(1))) unsigned int*)(g),
      (__attribute__((address_space(3))) unsigned int*)(l), 16, 0, 0);
}

__device__ __forceinline__ u16 f2bf(float f) {  // fp32 -> bf16 RNE
  unsigned int u = __builtin_bit_cast(unsigned int, f);
  u += 0x7FFFu + ((u >> 16) & 1u);
  return (u16)(u >> 16);
}

// ---------------------------------------------------------------------------
// fp32 -> bf16 conversion, 8 elems/thread
// ---------------------------------------------------------------------------
__global__ __launch_bounds__(256) void cvt_bf16(const float* __restrict__ in,
                                                u16* __restrict__ out, int n) {
  int i = (blockIdx.x * 256 + threadIdx.x) * 8;
  if (i >= n) return;
  float4 a = *(const float4*)(in + i);
  float4 b = *(const float4*)(in + i + 4);
  short8 o;
  o[0] = (short)f2bf(a.x); o[1] = (short)f2bf(a.y);
  o[2] = (short)f2bf(a.z); o[3] = (short)f2bf(a.w);
  o[4] = (short)f2bf(b.x); o[5] = (short)f2bf(b.y);
  o[6] = (short)f2bf(b.z); o[7] = (short)f2bf(b.w);
  *(short8*)(out + i) = o;
}

// ---------------------------------------------------------------------------
// bf16 MFMA GEMM (m97 structure): C[M,N] = A[M,K] * B[N,K]^T
// 128x128 tile, BK=32, 256 threads (2x2 waves, each 64x64 = 4x4 MFMA tiles).
// wbf!=0 -> store bf16 to Cb, else fp32 to Cf.
// ---------------------------------------------------------------------------
__global__ __launch_bounds__(256) void gemm_bt_bf16(const u16* __restrict__ A,
                                                    const u16* __restrict__ B,
                                                    u16* __restrict__ Cb,
                                                    float* __restrict__ Cf,
                                                    int M, int N, int K, int wbf) {
  __shared__ __align__(16) u16 As[128 * 32];  // row-major [128][32], 64B rows
  __shared__ __align__(16) u16 Bs[128 * 32];
  const int t = threadIdx.x;
  const int lane = t & 63, w = t >> 6;
  const int l15 = lane & 15, quad = lane >> 4;
  const int wm = w >> 1, wn = w & 1;
  const size_t m0 = (size_t)blockIdx.y * 128, n0 = (size_t)blockIdx.x * 128;

  const int srow = t >> 2;           // 0..63
  const int scol = (t & 3) * 8;      // 16B chunk within 64B row
  const u16* ga = A + (m0 + srow) * K + scol;
  const u16* gb = B + (n0 + srow) * K + scol;

  floatx4 acc[4][4] = {};

  for (int k0 = 0; k0 < K; k0 += 32) {
    __syncthreads();
    gload_lds16(ga + k0, &As[t * 8]);                       // rows 0..63
    gload_lds16(ga + (size_t)64 * K + k0, &As[2048 + t * 8]); // rows 64..127
    gload_lds16(gb + k0, &Bs[t * 8]);
    gload_lds16(gb + (size_t)64 * K + k0, &Bs[2048 + t * 8]);
    __syncthreads();
    short8 af[4], bfr[4];
#pragma unroll
    for (int mt = 0; mt < 4; ++mt)
      af[mt] = *(const short8*)&As[(wm * 64 + mt * 16 + l15) * 32 + quad * 8];
#pragma unroll
    for (int nt = 0; nt < 4; ++nt)
      bfr[nt] = *(const short8*)&Bs[(wn * 64 + nt * 16 + l15) * 32 + quad * 8];
#pragma unroll
    for (int mt = 0; mt < 4; ++mt)
#pragma unroll
      for (int nt = 0; nt < 4; ++nt)
        acc[mt][nt] = MFMA16(af[mt], bfr[nt], acc[mt][nt]);
  }

  // C/D layout: col = lane&15, row = quad*4 + reg
#pragma unroll
  for (int mt = 0; mt < 4; ++mt)
#pragma unroll
    for (int nt = 0; nt < 4; ++nt)
#pragma unroll
      for (int r = 0; r < 4; ++r) {
        size_t row = m0 + wm * 64 + mt * 16 + quad * 4 + r;
        size_t col = n0 + wn * 64 + nt * 16 + l15;
        if (wbf) Cb[row * N + col] = f2bf(acc[mt][nt][r]);
        else     Cf[row * N + col] = acc[mt][nt][r];
      }
}

// ---------------------------------------------------------------------------
// Flash attention (causal), bf16 MFMA. Block = 256 threads (4 waves),
// one block per (bh, 64-row q-tile). Wave w owns q rows w*16..w*16+15.
// LDS sub-tile layout [2][64][32] (64B rows) -> conflict-free b128 frag reads.
// ---------------------------------------------------------------------------
__global__ __launch_bounds__(256) void attn_mfma(const u16* __restrict__ qkv,
                                                 u16* __restrict__ y) {
  const int bh = blockIdx.y;
  const int b = bh >> 4, h = bh & 15;
  const int qt = blockIdx.x;
  const int t = threadIdx.x, lane = t & 63, w = t >> 6;
  const int l15 = lane & 15, quad = lane >> 4;

  __shared__ __align__(16) u16 Qs[2][64][32];  // sub = d-half
  __shared__ __align__(16) u16 Ks[2][64][32];  // sub = d-half
  __shared__ __align__(16) u16 Vt[2][64][32];  // sub = key-half, rows = d, cols = key&31 (chunk-XOR swizzled)
  __shared__ __align__(16) u16 Ps[2][64][32];  // sub = key-half, rows = q, cols = key&31 (chunk swizzled)

  const int srow = t >> 2;        // 0..63
  const int scol = (t & 3) * 8;   // 16B chunk

  // ---- stage Q ----
  {
    const u16* qp = qkv + ((size_t)(b * SEQ + qt * 64 + srow)) * QKV_LD + h * HDIM;
    gload_lds16(qp + scol,      &Qs[0][0][0] + t * 8);
    gload_lds16(qp + 32 + scol, &Qs[1][0][0] + t * 8);
  }
  __syncthreads();
  short8 qf0 = *(const short8*)&Qs[0][w * 16 + l15][quad * 8];
  short8 qf1 = *(const short8*)&Qs[1][w * 16 + l15][quad * 8];

  float m_r[4], l_r[4];
  floatx4 o_acc[4] = {};
#pragma unroll
  for (int r = 0; r < 4; ++r) { m_r[r] = -1e30f; l_r[r] = 0.0f; }

  for (int kt = 0; kt <= qt; ++kt) {
    __syncthreads();  // prior iteration's Ks/Vt/Ps readers done
    // ---- stage K tile ----
    {
      const u16* kp = qkv + ((size_t)(b * SEQ + kt * 64 + srow)) * QKV_LD + NEMBD + h * HDIM;
      gload_lds16(kp + scol,      &Ks[0][0][0] + t * 8);
      gload_lds16(kp + 32 + scol, &Ks[1][0][0] + t * 8);
    }
    // ---- load V, transpose into Vt (chunk-XOR swizzle) ----
#pragma unroll
    for (int j = 0; j < 2; ++j) {
      const int k = (t >> 3) + 32 * j;       // key row 0..63
      const int d0 = (t & 7) * 8;            // d chunk
      const u16* vp = qkv + ((size_t)(b * SEQ + kt * 64 + k)) * QKV_LD + 2 * NEMBD + h * HDIM + d0;
      short8 vv = *(const short8*)vp;
      const int sub = k >> 5;
      const int kc = (k & 31) >> 3, ko = k & 7;
#pragma unroll
      for (int i = 0; i < 8; ++i) {
        const int d = d0 + i;
        const int cp = (kc + (d >> 3)) & 3;
        Vt[sub][d][cp * 8 + ko] = (u16)vv[i];
      }
    }
    __syncthreads();

    // ---- S = scale * Q K^T ----
    float s4[4][4];
#pragma unroll
    for (int nt = 0; nt < 4; ++nt) {
      short8 kf0 = *(const short8*)&Ks[0][nt * 16 + l15][quad * 8];
      short8 kf1 = *(const short8*)&Ks[1][nt * 16 + l15][quad * 8];
      floatx4 sa = {0.f, 0.f, 0.f, 0.f};
      sa = MFMA16(qf0, kf0, sa);
      sa = MFMA16(qf1, kf1, sa);
#pragma unroll
      for (int r = 0; r < 4; ++r) {
        float sv = sa[r] * 0.125f;
        if (kt == qt && (nt * 16 + l15) > (w * 16 + quad * 4 + r)) sv = -1e30f;
        s4[nt][r] = sv;
      }
    }

    // ---- online softmax (in-register, quad-group shuffle reduce) ----
    float alpha[4];
#pragma unroll
    for (int r = 0; r < 4; ++r) {
      float mx = fmaxf(fmaxf(s4[0][r], s4[1][r]), fmaxf(s4[2][r], s4[3][r]));
#pragma unroll
      for (int off = 1; off < 16; off <<= 1) mx = fmaxf(mx, __shfl_xor(mx, off, 64));
      float nm = fmaxf(m_r[r], mx);
      float a = exp2f((m_r[r] - nm) * LOG2E);
      float rs = 0.0f;
#pragma unroll
      for (int nt = 0; nt < 4; ++nt) {
        float p = exp2f((s4[nt][r] - nm) * LOG2E);
        s4[nt][r] = p;
        rs += p;
      }
#pragma unroll
      for (int off = 1; off < 16; off <<= 1) rs += __shfl_xor(rs, off, 64);
      m_r[r] = nm;
      l_r[r] = l_r[r] * a + rs;
      alpha[r] = a;
    }

    // ---- write P (C-layout -> LDS, chunk swizzled); wave-local rows ----
#pragma unroll
    for (int nt = 0; nt < 4; ++nt)
#pragma unroll
      for (int r = 0; r < 4; ++r) {
        const int q = w * 16 + quad * 4 + r;
        const int col = nt * 16 + l15;
        const int sub = col >> 5;
        const int cp = (((col & 31) >> 3) + (q >> 3)) & 3;
        Ps[sub][q][cp * 8 + (col & 7)] = f2bf(s4[nt][r]);
      }

    // ---- O = O*alpha + P @ V ----
#pragma unroll
    for (int nt = 0; nt < 4; ++nt)
#pragma unroll
      for (int r = 0; r < 4; ++r) o_acc[nt][r] *= alpha[r];

    {
      const int qr = w * 16 + l15;
      const int qsw = qr >> 3;
      short8 pf0 = *(const short8*)&Ps[0][qr][((quad + qsw) & 3) * 8];
      short8 pf1 = *(const short8*)&Ps[1][qr][((quad + qsw) & 3) * 8];
#pragma unroll
      for (int nt = 0; nt < 4; ++nt) {
        const int d = nt * 16 + l15;
        const int cpv = ((quad + (d >> 3)) & 3) * 8;
        short8 vf0 = *(const short8*)&Vt[0][d][cpv];
        short8 vf1 = *(const short8*)&Vt[1][d][cpv];
        o_acc[nt] = MFMA16(pf0, vf0, o_acc[nt]);
        o_acc[nt] = MFMA16(pf1, vf1, o_acc[nt]);
      }
    }
  }

  // ---- epilogue: normalize, store y (bf16) ----
#pragma unroll
  for (int nt = 0; nt < 4; ++nt)
#pragma unroll
    for (int r = 0; r < 4; ++r) {
      const size_t grow = (size_t)(b * SEQ + qt * 64 + w * 16 + quad * 4 + r);
      float ov = o_acc[nt][r] / l_r[r];
      y[grow * NEMBD + h * HDIM + nt * 16 + l15] = f2bf(ov);
    }
}

// ---------------------------------------------------------------------------
extern "C" void kernel_launch(void* const* d_in, const int* in_sizes, int n_in,
                              void* d_out, int out_size, void* d_ws, size_t ws_size,
                              hipStream_t stream) {
  const float* x      = (const float*)d_in[0];   // [4096,1024]
  const float* w_attn = (const float*)d_in[1];   // [3072,1024]
  const float* w_proj = (const float*)d_in[2];   // [1024,1024]
  float* out = (float*)d_out;                    // [4096,1024] fp32

  u16* xb   = (u16*)d_ws;                                  // 8 MB
  u16* wab  = xb  + (size_t)BT * NEMBD;                    // 6 MB
  u16* wpb  = wab + (size_t)QKV_LD * NEMBD;                // 2 MB
  u16* qkvb = wpb + (size_t)NEMBD * NEMBD;                 // 25 MB
  u16* yb   = qkvb + (size_t)BT * QKV_LD;                  // 8 MB

  // fp32 -> bf16 conversions
  cvt_bf16<<<(BT * NEMBD) / 2048, 256, 0, stream>>>(x, xb, BT * NEMBD);
  cvt_bf16<<<(QKV_LD * NEMBD) / 2048, 256, 0, stream>>>(w_attn, wab, QKV_LD * NEMBD);
  cvt_bf16<<<(NEMBD * NEMBD) / 2048, 256, 0, stream>>>(w_proj, wpb, NEMBD * NEMBD);

  // qkv = x @ w_attn^T  -> bf16
  gemm_bt_bf16<<<dim3(QKV_LD / 128, BT / 128), 256, 0, stream>>>(
      xb, wab, qkvb, nullptr, BT, QKV_LD, NEMBD, 1);

  // fused causal attention -> y (bf16)
  attn_mfma<<<dim3(SEQ / 64, BSZ * NHEAD), 256, 0, stream>>>(qkvb, yb);

  // out = y @ w_proj^T -> fp32
  gemm_bt_bf16<<<dim3(NEMBD / 128, BT / 128), 256, 0, stream>>>(
      yb, wpb, nullptr, out, BT, NEMBD, NEMBD, 0);
}

// Round 3
// 235.479 us; speedup vs baseline: 5.3672x; 1.3226x over previous
//
#include <hip/hip_runtime.h>

// CausalSelfAttention: B=2, T=2048, C=1024, H=16, D=64 — bf16 MFMA, S^T-form flash attn.
#define BSZ 2
#define SEQ 2048
#define NEMBD 1024
#define NHEAD 16
#define HDIM 64
#define BT (BSZ * SEQ)          // 4096
#define QKV_LD (3 * NEMBD)      // 3072
#define SCALE_LOG2E 0.1803368665f   // (1/sqrt(64)) * log2(e)

typedef unsigned short u16;
typedef __attribute__((ext_vector_type(8))) short short8;     // 8 bf16 (MFMA A/B frag)
typedef __attribute__((ext_vector_type(4))) float floatx4;    // MFMA C/D frag
typedef __attribute__((ext_vector_type(4))) unsigned short ushort4v;

#define MFMA16(a, b, c) __builtin_amdgcn_mfma_f32_16x16x32_bf16(a, b, c, 0, 0, 0)

__device__ __forceinline__ void gload_lds16(const void* g, void* l) {
  __builtin_amdgcn_global_load_lds(
      (const __attribute__((address_space(1))) unsigned int*)(g),
      (__attribute__((address_space(3))) unsigned int*)(l), 16, 0, 0);
}

__device__ __forceinline__ u16 f2bf(float f) {  // fp32 -> bf16 RNE
  unsigned int u = __builtin_bit_cast(unsigned int, f);
  u += 0x7FFFu + ((u >> 16) & 1u);
  return (u16)(u >> 16);
}

// ---------------------------------------------------------------------------
__global__ __launch_bounds__(256) void cvt_bf16(const float* __restrict__ in,
                                                u16* __restrict__ out, int n) {
  int i = (blockIdx.x * 256 + threadIdx.x) * 8;
  if (i >= n) return;
  float4 a = *(const float4*)(in + i);
  float4 b = *(const float4*)(in + i + 4);
  short8 o;
  o[0] = (short)f2bf(a.x); o[1] = (short)f2bf(a.y);
  o[2] = (short)f2bf(a.z); o[3] = (short)f2bf(a.w);
  o[4] = (short)f2bf(b.x); o[5] = (short)f2bf(b.y);
  o[6] = (short)f2bf(b.z); o[7] = (short)f2bf(b.w);
  *(short8*)(out + i) = o;
}

// ---------------------------------------------------------------------------
// bf16 MFMA GEMM: C[M,N] = A[M,K] * B[N,K]^T. 128x128 tile, BK=32, 256 thr.
// wbf: 1 -> bf16 to Cb, 0 -> fp32 to Cf.
// VtG != null: columns >= 2048 (the V third of QKV) are stored TRANSPOSED
// into VtG layout [(b*16+h)*64+d][T] instead of Cb.
// ---------------------------------------------------------------------------
__global__ __launch_bounds__(256) void gemm_bt_bf16(const u16* __restrict__ A,
                                                    const u16* __restrict__ B,
                                                    u16* __restrict__ Cb,
                                                    float* __restrict__ Cf,
                                                    u16* __restrict__ VtG,
                                                    int M, int N, int K, int wbf) {
  __shared__ __align__(16) u16 As[128 * 32];
  __shared__ __align__(16) u16 Bs[128 * 32];
  const int t = threadIdx.x;
  const int lane = t & 63, w = t >> 6;
  const int l15 = lane & 15, quad = lane >> 4;
  const int wm = w >> 1, wn = w & 1;
  const int m0 = blockIdx.y * 128, n0 = blockIdx.x * 128;

  const int srow = t >> 2;
  const int scol = (t & 3) * 8;
  const u16* ga = A + (size_t)(m0 + srow) * K + scol;
  const u16* gb = B + (size_t)(n0 + srow) * K + scol;

  floatx4 acc[4][4] = {};

  for (int k0 = 0; k0 < K; k0 += 32) {
    __syncthreads();
    gload_lds16(ga + k0, &As[t * 8]);
    gload_lds16(ga + (size_t)64 * K + k0, &As[2048 + t * 8]);
    gload_lds16(gb + k0, &Bs[t * 8]);
    gload_lds16(gb + (size_t)64 * K + k0, &Bs[2048 + t * 8]);
    __syncthreads();
    short8 af[4], bfr[4];
#pragma unroll
    for (int mt = 0; mt < 4; ++mt)
      af[mt] = *(const short8*)&As[(wm * 64 + mt * 16 + l15) * 32 + quad * 8];
#pragma unroll
    for (int nt = 0; nt < 4; ++nt)
      bfr[nt] = *(const short8*)&Bs[(wn * 64 + nt * 16 + l15) * 32 + quad * 8];
#pragma unroll
    for (int mt = 0; mt < 4; ++mt)
#pragma unroll
      for (int nt = 0; nt < 4; ++nt)
        acc[mt][nt] = MFMA16(af[mt], bfr[nt], acc[mt][nt]);
  }

  if (VtG && n0 >= 2 * NEMBD) {
    // V third: store transposed. C row=token, col-2048 = h*64+d.
#pragma unroll
    for (int mt = 0; mt < 4; ++mt)
#pragma unroll
      for (int nt = 0; nt < 4; ++nt) {
        int hd = n0 + wn * 64 + nt * 16 + l15 - 2 * NEMBD;  // 0..1023
        int token = m0 + wm * 64 + mt * 16 + quad * 4;
        int b = token >> 11, tp = token & (SEQ - 1);
        ushort4v pk;
#pragma unroll
        for (int r = 0; r < 4; ++r) pk[r] = f2bf(acc[mt][nt][r]);
        *(ushort4v*)&VtG[((size_t)(b * NEMBD + hd)) * SEQ + tp] = pk;
      }
    return;
  }

#pragma unroll
  for (int mt = 0; mt < 4; ++mt)
#pragma unroll
    for (int nt = 0; nt < 4; ++nt)
#pragma unroll
      for (int r = 0; r < 4; ++r) {
        size_t row = (size_t)(m0 + wm * 64 + mt * 16 + quad * 4 + r);
        size_t col = (size_t)(n0 + wn * 64 + nt * 16 + l15);
        if (wbf) Cb[row * N + col] = f2bf(acc[mt][nt][r]);
        else     Cf[row * N + col] = acc[mt][nt][r];
      }
}

// ---------------------------------------------------------------------------
// Flash attention (causal), S^T form. Block = 256 thr (4 waves), Q-tile 128
// (wave owns 32 q as S^T columns), K-tile 64.
// All staged LDS tiles are [rows][64 u16] with chunk-XOR swizzle:
// element [row][c] lives at row*64 + ((c>>3) ^ (row&7))*8 + (c&7).
// ---------------------------------------------------------------------------
__global__ __launch_bounds__(256) void attn_mfma2(const u16* __restrict__ qkv,
                                                  const u16* __restrict__ vtg,
                                                  u16* __restrict__ y) {
  const int bx = blockIdx.x;
  const int bh = bx & 31;
  const int ii = bx >> 5;                       // 0..15
  const int qt = (ii < 8) ? (15 - ii) : (ii - 8);  // big tiles dispatch first
  const int b = bh >> 4, h = bh & 15;
  const int t = threadIdx.x, lane = t & 63, w = t >> 6;
  const int l15 = lane & 15, quad = lane >> 4;

  __shared__ __align__(16) u16 Qs[128 * 64];  // [q][d] swizzled      16 KB
  __shared__ __align__(16) u16 Ks[64 * 64];   // [key][d] swizzled     8 KB
  __shared__ __align__(16) u16 Vt[64 * 64];   // [d][key] swizzled     8 KB
  __shared__ __align__(16) u16 Pa[128 * 72];  // [q][key], pad 72     18 KB

  // ---- stage Q (128 rows) ----
  {
    const u16* qb = qkv + ((size_t)(b * SEQ + qt * 128)) * QKV_LD + h * HDIM;
#pragma unroll
    for (int is = 0; is < 4; ++is) {
      int s = is * 256 + t;
      int row = s >> 3, pos = s & 7;
      int kc = pos ^ (row & 7);
      gload_lds16(qb + (size_t)row * QKV_LD + kc * 8, &Qs[s * 8]);
    }
  }
  __syncthreads();
  short8 qf[2][2];
#pragma unroll
  for (int qs = 0; qs < 2; ++qs) {
    int qrow = w * 32 + qs * 16 + l15;
#pragma unroll
    for (int hf = 0; hf < 2; ++hf)
      qf[qs][hf] = *(const short8*)&Qs[qrow * 64 + (((hf * 4 + quad) ^ (qrow & 7)) * 8)];
  }

  float m_s[2] = {-1e30f, -1e30f}, l_s[2] = {0.f, 0.f};
  floatx4 o_acc[2][4] = {};

  const int ktmax = 2 * qt + 2;
  for (int kt = 0; kt < ktmax; ++kt) {
    // ---- stage K tile + V^T tile ----
    {
      const u16* kb = qkv + ((size_t)(b * SEQ + kt * 64)) * QKV_LD + NEMBD + h * HDIM;
      const u16* vb = vtg + ((size_t)(bh * 64)) * SEQ + kt * 64;
#pragma unroll
      for (int is = 0; is < 2; ++is) {
        int s = is * 256 + t;
        int row = s >> 3, pos = s & 7;
        int kc = pos ^ (row & 7);
        gload_lds16(kb + (size_t)row * QKV_LD + kc * 8, &Ks[s * 8]);
        gload_lds16(vb + (size_t)row * SEQ + kc * 8, &Vt[s * 8]);
      }
    }
    __syncthreads();

    // ---- S^T = K Q^T : rows = key (quad*4+r), cols = q (l15) ----
    floatx4 sacc[2][4];
#pragma unroll
    for (int nt = 0; nt < 4; ++nt) {
      int krow = nt * 16 + l15;
      short8 kf0 = *(const short8*)&Ks[krow * 64 + ((quad ^ (krow & 7)) * 8)];
      short8 kf1 = *(const short8*)&Ks[krow * 64 + (((4 + quad) ^ (krow & 7)) * 8)];
#pragma unroll
      for (int qs = 0; qs < 2; ++qs) {
        floatx4 z = {0.f, 0.f, 0.f, 0.f};
        z = MFMA16(kf0, qf[qs][0], z);
        z = MFMA16(kf1, qf[qs][1], z);
        sacc[qs][nt] = z;
      }
    }

    // ---- online softmax (log2 domain), P -> Pa as b64 stores ----
    const int mask_on = (kt >= 2 * qt);
    float alpha[2];
#pragma unroll
    for (int qs = 0; qs < 2; ++qs) {
      const int qg = qt * 128 + w * 32 + qs * 16 + l15;
      const int kb0 = kt * 64 + quad * 4;
      float sv[4][4];
      float mloc = -1e30f;
#pragma unroll
      for (int nt = 0; nt < 4; ++nt)
#pragma unroll
        for (int r = 0; r < 4; ++r) {
          float v = sacc[qs][nt][r] * SCALE_LOG2E;
          if (mask_on && (kb0 + nt * 16 + r) > qg) v = -1e30f;
          sv[nt][r] = v;
          mloc = fmaxf(mloc, v);
        }
      mloc = fmaxf(mloc, __shfl_xor(mloc, 16, 64));
      mloc = fmaxf(mloc, __shfl_xor(mloc, 32, 64));
      float nm = fmaxf(m_s[qs], mloc);
      float a = exp2f(m_s[qs] - nm);
      float rs = 0.f;
#pragma unroll
      for (int nt = 0; nt < 4; ++nt) {
        ushort4v pk;
#pragma unroll
        for (int r = 0; r < 4; ++r) {
          float p = exp2f(sv[nt][r] - nm);
          rs += p;
          pk[r] = f2bf(p);
        }
        *(ushort4v*)&Pa[(w * 32 + qs * 16 + l15) * 72 + nt * 16 + quad * 4] = pk;
      }
      rs += __shfl_xor(rs, 16, 64);
      rs += __shfl_xor(rs, 32, 64);
      m_s[qs] = nm;
      l_s[qs] = l_s[qs] * a + rs;
      alpha[qs] = a;
    }

    // ---- O *= alpha (broadcast l15-domain -> C-row domain) ----
#pragma unroll
    for (int qs = 0; qs < 2; ++qs) {
      float ar[4];
#pragma unroll
      for (int r = 0; r < 4; ++r) ar[r] = __shfl(alpha[qs], quad * 4 + r, 64);
#pragma unroll
      for (int nt = 0; nt < 4; ++nt)
#pragma unroll
        for (int r = 0; r < 4; ++r) o_acc[qs][nt][r] *= ar[r];
    }

    // ---- O += P @ V ----
    {
      short8 pf[2][2];
#pragma unroll
      for (int qs = 0; qs < 2; ++qs) {
        const int prow = w * 32 + qs * 16 + l15;
        pf[qs][0] = *(const short8*)&Pa[prow * 72 + quad * 8];
        pf[qs][1] = *(const short8*)&Pa[prow * 72 + 32 + quad * 8];
      }
#pragma unroll
      for (int nt = 0; nt < 4; ++nt) {
        int drow = nt * 16 + l15;
        short8 vf0 = *(const short8*)&Vt[drow * 64 + ((quad ^ (drow & 7)) * 8)];
        short8 vf1 = *(const short8*)&Vt[drow * 64 + (((4 + quad) ^ (drow & 7)) * 8)];
#pragma unroll
        for (int qs = 0; qs < 2; ++qs) {
          o_acc[qs][nt] = MFMA16(pf[qs][0], vf0, o_acc[qs][nt]);
          o_acc[qs][nt] = MFMA16(pf[qs][1], vf1, o_acc[qs][nt]);
        }
      }
    }
    __syncthreads();
  }

  // ---- epilogue ----
  float linv[2][4];
#pragma unroll
  for (int qs = 0; qs < 2; ++qs)
#pragma unroll
    for (int r = 0; r < 4; ++r)
      linv[qs][r] = 1.0f / __shfl(l_s[qs], quad * 4 + r, 64);

#pragma unroll
  for (int qs = 0; qs < 2; ++qs)
#pragma unroll
    for (int nt = 0; nt < 4; ++nt)
#pragma unroll
      for (int r = 0; r < 4; ++r) {
        int qlocal = w * 32 + qs * 16 + quad * 4 + r;
        size_t tok = (size_t)(b * SEQ + qt * 128 + qlocal);
        y[tok * NEMBD + h * HDIM + nt * 16 + l15] = f2bf(o_acc[qs][nt][r] * linv[qs][r]);
      }
}

// ---------------------------------------------------------------------------
extern "C" void kernel_launch(void* const* d_in, const int* in_sizes, int n_in,
                              void* d_out, int out_size, void* d_ws, size_t ws_size,
                              hipStream_t stream) {
  const float* x      = (const float*)d_in[0];
  const float* w_attn = (const float*)d_in[1];
  const float* w_proj = (const float*)d_in[2];
  float* out = (float*)d_out;

  u16* xb   = (u16*)d_ws;                       // 8 MB
  u16* wab  = xb   + (size_t)BT * NEMBD;        // 6 MB
  u16* wpb  = wab  + (size_t)QKV_LD * NEMBD;    // 2 MB
  u16* qkvb = wpb  + (size_t)NEMBD * NEMBD;     // 24 MB (V third unused)
  u16* vtg  = qkvb + (size_t)BT * QKV_LD;       // 8 MB  [bh*64+d][T]
  u16* yb   = vtg  + (size_t)BT * NEMBD;        // 8 MB

  cvt_bf16<<<(BT * NEMBD) / 2048, 256, 0, stream>>>(x, xb, BT * NEMBD);
  cvt_bf16<<<(QKV_LD * NEMBD) / 2048, 256, 0, stream>>>(w_attn, wab, QKV_LD * NEMBD);
  cvt_bf16<<<(NEMBD * NEMBD) / 2048, 256, 0, stream>>>(w_proj, wpb, NEMBD * NEMBD);

  // qkv = x @ w_attn^T (Q,K thirds -> qkvb bf16; V third -> vtg transposed)
  gemm_bt_bf16<<<dim3(QKV_LD / 128, BT / 128), 256, 0, stream>>>(
      xb, wab, qkvb, nullptr, vtg, BT, QKV_LD, NEMBD, 1);

  // fused causal attention -> yb (bf16)
  attn_mfma2<<<dim3((SEQ / 128) * BSZ * NHEAD), 256, 0, stream>>>(qkvb, vtg, yb);

  // out = yb @ w_proj^T -> fp32
  gemm_bt_bf16<<<dim3(NEMBD / 128, BT / 128), 256, 0, stream>>>(
      yb, wpb, nullptr, out, nullptr, BT, NEMBD, NEMBD, 0);
}

// Round 4
// 205.029 us; speedup vs baseline: 6.1644x; 1.1485x over previous
//
#include <hip/hip_runtime.h>

// CausalSelfAttention: B=2, T=2048, C=1024, H=16, D=64
// bf16 MFMA, S^T-form flash attention, fixed-C softmax, 2-way split-K.
#define BSZ 2
#define SEQ 2048
#define NEMBD 1024
#define NHEAD 16
#define HDIM 64
#define BT (BSZ * SEQ)          // 4096
#define QKV_LD (3 * NEMBD)      // 3072
#define SCALE_LOG2E 0.1803368665f   // (1/sqrt(64)) * log2(e)

typedef unsigned short u16;
typedef __attribute__((ext_vector_type(8))) short short8;     // 8 bf16 (MFMA A/B frag)
typedef __attribute__((ext_vector_type(4))) float floatx4;    // MFMA C/D frag
typedef __attribute__((ext_vector_type(4))) unsigned short ushort4v;

#define MFMA16(a, b, c) __builtin_amdgcn_mfma_f32_16x16x32_bf16(a, b, c, 0, 0, 0)

__device__ __forceinline__ void gload_lds16(const void* g, void* l) {
  __builtin_amdgcn_global_load_lds(
      (const __attribute__((address_space(1))) unsigned int*)(g),
      (__attribute__((address_space(3))) unsigned int*)(l), 16, 0, 0);
}

__device__ __forceinline__ u16 f2bf(float f) {  // fp32 -> bf16 RNE
  unsigned int u = __builtin_bit_cast(unsigned int, f);
  u += 0x7FFFu + ((u >> 16) & 1u);
  return (u16)(u >> 16);
}

// ---------------------------------------------------------------------------
__global__ __launch_bounds__(256) void cvt_bf16(const float* __restrict__ in,
                                                u16* __restrict__ out, int n) {
  int i = (blockIdx.x * 256 + threadIdx.x) * 8;
  if (i >= n) return;
  float4 a = *(const float4*)(in + i);
  float4 b = *(const float4*)(in + i + 4);
  short8 o;
  o[0] = (short)f2bf(a.x); o[1] = (short)f2bf(a.y);
  o[2] = (short)f2bf(a.z); o[3] = (short)f2bf(a.w);
  o[4] = (short)f2bf(b.x); o[5] = (short)f2bf(b.y);
  o[6] = (short)f2bf(b.z); o[7] = (short)f2bf(b.w);
  *(short8*)(out + i) = o;
}

// ---------------------------------------------------------------------------
// GEMM1: qkv = x @ w_attn^T. 128x128 tile, BK=32.
// n0 < 2048: Q,K thirds -> qkb [4096][2048] bf16.
// n0 >= 2048: V third -> vtg [(b*16+h)*64+d][T] bf16 (transposed).
// ---------------------------------------------------------------------------
__global__ __launch_bounds__(256) void gemm_qkv(const u16* __restrict__ A,
                                                const u16* __restrict__ B,
                                                u16* __restrict__ qkb,
                                                u16* __restrict__ vtg) {
  __shared__ __align__(16) u16 As[128 * 32];
  __shared__ __align__(16) u16 Bs[128 * 32];
  const int t = threadIdx.x;
  const int lane = t & 63, w = t >> 6;
  const int l15 = lane & 15, quad = lane >> 4;
  const int wm = w >> 1, wn = w & 1;
  const int m0 = blockIdx.y * 128, n0 = blockIdx.x * 128;

  const int srow = t >> 2;
  const int scol = (t & 3) * 8;
  const u16* ga = A + (size_t)(m0 + srow) * NEMBD + scol;
  const u16* gb = B + (size_t)(n0 + srow) * NEMBD + scol;

  floatx4 acc[4][4] = {};

  for (int k0 = 0; k0 < NEMBD; k0 += 32) {
    __syncthreads();
    gload_lds16(ga + k0, &As[t * 8]);
    gload_lds16(ga + (size_t)64 * NEMBD + k0, &As[2048 + t * 8]);
    gload_lds16(gb + k0, &Bs[t * 8]);
    gload_lds16(gb + (size_t)64 * NEMBD + k0, &Bs[2048 + t * 8]);
    __syncthreads();
    short8 af[4], bfr[4];
#pragma unroll
    for (int mt = 0; mt < 4; ++mt)
      af[mt] = *(const short8*)&As[(wm * 64 + mt * 16 + l15) * 32 + quad * 8];
#pragma unroll
    for (int nt = 0; nt < 4; ++nt)
      bfr[nt] = *(const short8*)&Bs[(wn * 64 + nt * 16 + l15) * 32 + quad * 8];
#pragma unroll
    for (int mt = 0; mt < 4; ++mt)
#pragma unroll
      for (int nt = 0; nt < 4; ++nt)
        acc[mt][nt] = MFMA16(af[mt], bfr[nt], acc[mt][nt]);
  }

  if (n0 >= 2 * NEMBD) {
#pragma unroll
    for (int mt = 0; mt < 4; ++mt)
#pragma unroll
      for (int nt = 0; nt < 4; ++nt) {
        int hd = n0 + wn * 64 + nt * 16 + l15 - 2 * NEMBD;
        int token = m0 + wm * 64 + mt * 16 + quad * 4;
        int b = token >> 11, tp = token & (SEQ - 1);
        ushort4v pk;
#pragma unroll
        for (int r = 0; r < 4; ++r) pk[r] = f2bf(acc[mt][nt][r]);
        *(ushort4v*)&vtg[((size_t)(b * NEMBD + hd)) * SEQ + tp] = pk;
      }
  } else {
#pragma unroll
    for (int mt = 0; mt < 4; ++mt)
#pragma unroll
      for (int nt = 0; nt < 4; ++nt)
#pragma unroll
        for (int r = 0; r < 4; ++r) {
          size_t row = (size_t)(m0 + wm * 64 + mt * 16 + quad * 4 + r);
          size_t col = (size_t)(n0 + wn * 64 + nt * 16 + l15);
          qkb[row * 2048 + col] = f2bf(acc[mt][nt][r]);
        }
  }
}

// ---------------------------------------------------------------------------
// Flash attention (causal), S^T form, fixed-C softmax (C=8), 2-way split-K.
// Block = 256 thr (4 waves). Q-tile 128 (wave owns 32 q-cols), K-tile 64.
// grid.x = 16 qt * 32 bh * 2 half = 1024; big q-tiles dispatch first.
// Writes UNNORMALIZED O partial (bf16) + l partial (fp32).
// ---------------------------------------------------------------------------
__global__ __launch_bounds__(256) void attn_mfma3(const u16* __restrict__ qkb,
                                                  const u16* __restrict__ vtg,
                                                  u16* __restrict__ opart,
                                                  float* __restrict__ lpart) {
  const int bx = blockIdx.x;
  const int qt = 15 - (bx >> 6);
  const int r6 = bx & 63;
  const int bh = r6 >> 1, half = r6 & 1;
  const int b = bh >> 4, h = bh & 15;
  const int t = threadIdx.x, lane = t & 63, w = t >> 6;
  const int l15 = lane & 15, quad = lane >> 4;

  __shared__ __align__(16) u16 Qs[128 * 64];  // [q][d] swizzled      16 KB
  __shared__ __align__(16) u16 Ks[64 * 64];   // [key][d] swizzled     8 KB
  __shared__ __align__(16) u16 Vt[64 * 64];   // [d][key] swizzled     8 KB
  __shared__ __align__(16) u16 Pa[128 * 72];  // [q][key], pad 72     18 KB

  // ---- stage Q (128 rows, swizzle ((c>>3)^(row&7))) ----
  {
    const u16* qb = qkb + ((size_t)(b * SEQ + qt * 128)) * 2048 + h * HDIM;
#pragma unroll
    for (int is = 0; is < 4; ++is) {
      int s = is * 256 + t;
      int row = s >> 3, pos = s & 7;
      int kc = pos ^ (row & 7);
      gload_lds16(qb + (size_t)row * 2048 + kc * 8, &Qs[s * 8]);
    }
  }
  __syncthreads();
  short8 qf[2][2];
#pragma unroll
  for (int qs = 0; qs < 2; ++qs) {
    int qrow = w * 32 + qs * 16 + l15;
#pragma unroll
    for (int hf = 0; hf < 2; ++hf)
      qf[qs][hf] = *(const short8*)&Qs[qrow * 64 + (((hf * 4 + quad) ^ (qrow & 7)) * 8)];
  }

  float rs[2] = {0.f, 0.f};
  floatx4 o_acc[2][4] = {};

  const int kt0 = half ? (qt + 1) : 0;
  const int kt_end = kt0 + qt + 1;
  const int um_end = (kt_end < 2 * qt) ? kt_end : (2 * qt);

#define ATTN_TILE(KT, MASKED)                                                  \
  {                                                                            \
    __syncthreads();                                                           \
    const u16* kb = qkb + ((size_t)(b * SEQ + (KT) * 64)) * 2048 + NEMBD + h * HDIM; \
    const u16* vb = vtg + ((size_t)(bh * 64)) * SEQ + (KT) * 64;               \
    _Pragma("unroll")                                                          \
    for (int is = 0; is < 2; ++is) {                                           \
      int s = is * 256 + t;                                                    \
      int row = s >> 3, pos = s & 7;                                           \
      int kc = pos ^ (row & 7);                                                \
      gload_lds16(kb + (size_t)row * 2048 + kc * 8, &Ks[s * 8]);               \
      gload_lds16(vb + (size_t)row * SEQ + kc * 8, &Vt[s * 8]);                \
    }                                                                          \
    __syncthreads();                                                           \
    floatx4 sacc[2][4];                                                        \
    _Pragma("unroll")                                                          \
    for (int nt = 0; nt < 4; ++nt) {                                           \
      int krow = nt * 16 + l15;                                                \
      short8 kf0 = *(const short8*)&Ks[krow * 64 + ((quad ^ (krow & 7)) * 8)]; \
      short8 kf1 = *(const short8*)&Ks[krow * 64 + (((4 + quad) ^ (krow & 7)) * 8)]; \
      _Pragma("unroll")                                                        \
      for (int qs = 0; qs < 2; ++qs) {                                         \
        floatx4 z = {0.f, 0.f, 0.f, 0.f};                                      \
        z = MFMA16(kf0, qf[qs][0], z);                                         \
        z = MFMA16(kf1, qf[qs][1], z);                                         \
        sacc[qs][nt] = z;                                                      \
      }                                                                        \
    }                                                                          \
    _Pragma("unroll")                                                          \
    for (int qs = 0; qs < 2; ++qs) {                                           \
      const int qg = qt * 128 + w * 32 + qs * 16 + l15;                        \
      const int kb0 = (KT) * 64 + quad * 4;                                    \
      _Pragma("unroll")                                                        \
      for (int nt = 0; nt < 4; ++nt) {                                         \
        ushort4v pk;                                                           \
        _Pragma("unroll")                                                      \
        for (int r = 0; r < 4; ++r) {                                          \
          float p = exp2f(fmaf(sacc[qs][nt][r], SCALE_LOG2E, -8.0f));          \
          if (MASKED && (kb0 + nt * 16 + r) > qg) p = 0.0f;                    \
          rs[qs] += p;                                                         \
          pk[r] = f2bf(p);                                                     \
        }                                                                      \
        *(ushort4v*)&Pa[(w * 32 + qs * 16 + l15) * 72 + nt * 16 + quad * 4] = pk; \
      }                                                                        \
    }                                                                          \
    short8 pf[2][2];                                                           \
    _Pragma("unroll")                                                          \
    for (int qs = 0; qs < 2; ++qs) {                                           \
      const int prow = w * 32 + qs * 16 + l15;                                 \
      pf[qs][0] = *(const short8*)&Pa[prow * 72 + quad * 8];                   \
      pf[qs][1] = *(const short8*)&Pa[prow * 72 + 32 + quad * 8];              \
    }                                                                          \
    _Pragma("unroll")                                                          \
    for (int nt = 0; nt < 4; ++nt) {                                           \
      int drow = nt * 16 + l15;                                                \
      short8 vf0 = *(const short8*)&Vt[drow * 64 + ((quad ^ (drow & 7)) * 8)]; \
      short8 vf1 = *(const short8*)&Vt[drow * 64 + (((4 + quad) ^ (drow & 7)) * 8)]; \
      _Pragma("unroll")                                                        \
      for (int qs = 0; qs < 2; ++qs) {                                         \
        o_acc[qs][nt] = MFMA16(pf[qs][0], vf0, o_acc[qs][nt]);                 \
        o_acc[qs][nt] = MFMA16(pf[qs][1], vf1, o_acc[qs][nt]);                 \
      }                                                                        \
    }                                                                          \
  }

  int kt = kt0;
  for (; kt < um_end; ++kt) ATTN_TILE(kt, 0);
  for (; kt < kt_end; ++kt) ATTN_TILE(kt, 1);
#undef ATTN_TILE

  // ---- epilogue: reduce l over quads, store partials ----
#pragma unroll
  for (int qs = 0; qs < 2; ++qs) {
    rs[qs] += __shfl_xor(rs[qs], 16, 64);
    rs[qs] += __shfl_xor(rs[qs], 32, 64);
    if (quad == 0)
      lpart[((size_t)half * 32 + bh) * SEQ + qt * 128 + w * 32 + qs * 16 + l15] = rs[qs];
  }
  u16* ob = opart + (size_t)half * BT * NEMBD;
#pragma unroll
  for (int qs = 0; qs < 2; ++qs)
#pragma unroll
    for (int nt = 0; nt < 4; ++nt)
#pragma unroll
      for (int r = 0; r < 4; ++r) {
        size_t tok = (size_t)(b * SEQ + qt * 128 + w * 32 + qs * 16 + quad * 4 + r);
        ob[tok * NEMBD + h * HDIM + nt * 16 + l15] = f2bf(o_acc[qs][nt][r]);
      }
}

// ---------------------------------------------------------------------------
// Combine split-K partials: yb = (O0 + O1) / (l0 + l1), bf16.
// ---------------------------------------------------------------------------
__global__ __launch_bounds__(256) void combine(const u16* __restrict__ opart,
                                               const float* __restrict__ lpart,
                                               u16* __restrict__ yb) {
  int idx = (blockIdx.x * 256 + threadIdx.x) * 4;
  int tok = idx >> 10, c = idx & 1023;
  int b = tok >> 11, q = tok & (SEQ - 1), h = c >> 6;
  float l = lpart[(size_t)(b * 16 + h) * SEQ + q] +
            lpart[(size_t)(32 + b * 16 + h) * SEQ + q];
  float inv = 1.0f / l;
  ushort4v o0 = *(const ushort4v*)&opart[idx];
  ushort4v o1 = *(const ushort4v*)&opart[(size_t)BT * NEMBD + idx];
  ushort4v yo;
#pragma unroll
  for (int j = 0; j < 4; ++j) {
    float f0 = __builtin_bit_cast(float, (unsigned)o0[j] << 16);
    float f1 = __builtin_bit_cast(float, (unsigned)o1[j] << 16);
    yo[j] = f2bf((f0 + f1) * inv);
  }
  *(ushort4v*)&yb[idx] = yo;
}

// ---------------------------------------------------------------------------
// GEMM2: out(fp32) = yb @ w_proj^T. 128x64 tile, BK=32 -> 512 blocks.
// ---------------------------------------------------------------------------
__global__ __launch_bounds__(256) void gemm_out(const u16* __restrict__ A,
                                                const u16* __restrict__ B,
                                                float* __restrict__ C) {
  __shared__ __align__(16) u16 As[128 * 32];
  __shared__ __align__(16) u16 Bs[64 * 32];
  const int t = threadIdx.x;
  const int lane = t & 63, w = t >> 6;
  const int l15 = lane & 15, quad = lane >> 4;
  const int wm = w >> 1, wn = w & 1;
  const int m0 = blockIdx.y * 128, n0 = blockIdx.x * 64;

  const int srow = t >> 2;
  const int scol = (t & 3) * 8;
  const u16* ga = A + (size_t)(m0 + srow) * NEMBD + scol;
  const u16* gb = B + (size_t)(n0 + srow) * NEMBD + scol;  // srow<64 rows used

  floatx4 acc[4][2] = {};

  for (int k0 = 0; k0 < NEMBD; k0 += 32) {
    __syncthreads();
    gload_lds16(ga + k0, &As[t * 8]);
    gload_lds16(ga + (size_t)64 * NEMBD + k0, &As[2048 + t * 8]);
    gload_lds16(gb + k0, &Bs[t * 8]);
    __syncthreads();
    short8 af[4], bfr[2];
#pragma unroll
    for (int mt = 0; mt < 4; ++mt)
      af[mt] = *(const short8*)&As[(wm * 64 + mt * 16 + l15) * 32 + quad * 8];
#pragma unroll
    for (int nt = 0; nt < 2; ++nt)
      bfr[nt] = *(const short8*)&Bs[(wn * 32 + nt * 16 + l15) * 32 + quad * 8];
#pragma unroll
    for (int mt = 0; mt < 4; ++mt)
#pragma unroll
      for (int nt = 0; nt < 2; ++nt)
        acc[mt][nt] = MFMA16(af[mt], bfr[nt], acc[mt][nt]);
  }

#pragma unroll
  for (int mt = 0; mt < 4; ++mt)
#pragma unroll
    for (int nt = 0; nt < 2; ++nt)
#pragma unroll
      for (int r = 0; r < 4; ++r) {
        size_t row = (size_t)(m0 + wm * 64 + mt * 16 + quad * 4 + r);
        size_t col = (size_t)(n0 + wn * 32 + nt * 16 + l15);
        C[row * NEMBD + col] = acc[mt][nt][r];
      }
}

// ---------------------------------------------------------------------------
extern "C" void kernel_launch(void* const* d_in, const int* in_sizes, int n_in,
                              void* d_out, int out_size, void* d_ws, size_t ws_size,
                              hipStream_t stream) {
  const float* x      = (const float*)d_in[0];
  const float* w_attn = (const float*)d_in[1];
  const float* w_proj = (const float*)d_in[2];
  float* out = (float*)d_out;

  // Workspace (u16 units). opart ALIASES xb+wab: xb/wab dead after gemm_qkv,
  // opart written by attn_mfma3 (later in stream). Total ~53 MB.
  u16* base  = (u16*)d_ws;
  u16* opart = base;                       // 2*4096*1024 u16 = 16 MB
  u16* xb    = base;                       // 4096*1024 (alias, dead after GEMM1)
  u16* wab   = base + 4194304;             // 3072*1024 (alias, dead after GEMM1)
  u16* wpb   = base + 8388608;             // 1024*1024 = 2 MB
  u16* qkb   = base + 9437184;             // 4096*2048 = 16 MB
  u16* vtg   = base + 17825792;            // 4096*1024 = 8 MB
  u16* yb    = base + 22020096;            // 4096*1024 = 8 MB
  float* lpart = (float*)(base + 26214400);  // 2*32*2048 fp32 = 0.5 MB

  cvt_bf16<<<(BT * NEMBD) / 2048, 256, 0, stream>>>(x, xb, BT * NEMBD);
  cvt_bf16<<<(QKV_LD * NEMBD) / 2048, 256, 0, stream>>>(w_attn, wab, QKV_LD * NEMBD);
  cvt_bf16<<<(NEMBD * NEMBD) / 2048, 256, 0, stream>>>(w_proj, wpb, NEMBD * NEMBD);

  gemm_qkv<<<dim3(QKV_LD / 128, BT / 128), 256, 0, stream>>>(xb, wab, qkb, vtg);

  attn_mfma3<<<dim3((SEQ / 128) * BSZ * NHEAD * 2), 256, 0, stream>>>(qkb, vtg, opart, lpart);

  combine<<<(BT * NEMBD) / 1024, 256, 0, stream>>>(opart, lpart, yb);

  gemm_out<<<dim3(NEMBD / 64, BT / 128), 256, 0, stream>>>(yb, wpb, out);
}

// Round 5
// 204.525 us; speedup vs baseline: 6.1795x; 1.0025x over previous
//
#include <hip/hip_runtime.h>

// CausalSelfAttention: B=2, T=2048, C=1024, H=16, D=64
// bf16 MFMA; BK=64 XOR-swizzled GEMMs w/ operand-swapped epilogues;
// S^T-form flash attention, fixed-C softmax, 2-way split-K.
#define BSZ 2
#define SEQ 2048
#define NEMBD 1024
#define NHEAD 16
#define HDIM 64
#define BT (BSZ * SEQ)          // 4096
#define QKV_LD (3 * NEMBD)      // 3072
#define SCALE_LOG2E 0.1803368665f   // (1/sqrt(64)) * log2(e)

typedef unsigned short u16;
typedef __attribute__((ext_vector_type(8))) short short8;     // 8 bf16 (MFMA A/B frag)
typedef __attribute__((ext_vector_type(4))) float floatx4;    // MFMA C/D frag
typedef __attribute__((ext_vector_type(4))) unsigned short ushort4v;

#define MFMA16(a, b, c) __builtin_amdgcn_mfma_f32_16x16x32_bf16(a, b, c, 0, 0, 0)

__device__ __forceinline__ void gload_lds16(const void* g, void* l) {
  __builtin_amdgcn_global_load_lds(
      (const __attribute__((address_space(1))) unsigned int*)(g),
      (__attribute__((address_space(3))) unsigned int*)(l), 16, 0, 0);
}

__device__ __forceinline__ u16 f2bf(float f) {  // fp32 -> bf16 RNE
  unsigned int u = __builtin_bit_cast(unsigned int, f);
  u += 0x7FFFu + ((u >> 16) & 1u);
  return (u16)(u >> 16);
}

// ---------------------------------------------------------------------------
// Fused fp32->bf16 conversion of x, w_attn, w_proj in one launch.
// ---------------------------------------------------------------------------
#define N_X  (BT * NEMBD)          // 4194304
#define N_WA (QKV_LD * NEMBD)      // 3145728
#define N_WP (NEMBD * NEMBD)       // 1048576
__global__ __launch_bounds__(256) void cvt_all(const float* __restrict__ x,
                                               const float* __restrict__ wa,
                                               const float* __restrict__ wp,
                                               u16* __restrict__ xb,
                                               u16* __restrict__ wab,
                                               u16* __restrict__ wpb) {
  int i = (blockIdx.x * 256 + threadIdx.x) * 8;
  const float* src;
  u16* dst;
  if (i < N_X)            { src = x + i;              dst = xb + i; }
  else if (i < N_X + N_WA){ src = wa + (i - N_X);     dst = wab + (i - N_X); }
  else                    { src = wp + (i - N_X - N_WA); dst = wpb + (i - N_X - N_WA); }
  float4 a = *(const float4*)(src);
  float4 b = *(const float4*)(src + 4);
  short8 o;
  o[0] = (short)f2bf(a.x); o[1] = (short)f2bf(a.y);
  o[2] = (short)f2bf(a.z); o[3] = (short)f2bf(a.w);
  o[4] = (short)f2bf(b.x); o[5] = (short)f2bf(b.y);
  o[6] = (short)f2bf(b.z); o[7] = (short)f2bf(b.w);
  *(short8*)(dst) = o;
}

// ---------------------------------------------------------------------------
// GEMM1: qkv = x @ w_attn^T. 128x128 tile, BK=64, XOR-swizzled LDS.
// LDS element [row][c] (c = u16 col 0..63) at row*64 + (((c>>3) ^ (row&7))*8 + (c&7)).
// n0 < 2048 (Q,K): operand-SWAPPED MFMA -> lane packs 4 consecutive n -> b64 stores.
// n0 >= 2048 (V): normal order -> lane packs 4 consecutive tokens -> vtg b64 stores.
// ---------------------------------------------------------------------------
__global__ __launch_bounds__(256) void gemm_qkv(const u16* __restrict__ A,
                                                const u16* __restrict__ B,
                                                u16* __restrict__ qkb,
                                                u16* __restrict__ vtg) {
  __shared__ __align__(16) u16 As[128 * 64];  // 16 KB
  __shared__ __align__(16) u16 Bs[128 * 64];  // 16 KB
  const int t = threadIdx.x;
  const int lane = t & 63, w = t >> 6;
  const int l15 = lane & 15, quad = lane >> 4;
  const int wm = w >> 1, wn = w & 1;
  const int m0 = blockIdx.y * 128, n0 = blockIdx.x * 128;
  const int is_v = (n0 >= 2 * NEMBD);

  floatx4 acc[4][4] = {};

  for (int k0 = 0; k0 < NEMBD; k0 += 64) {
    __syncthreads();
#pragma unroll
    for (int is = 0; is < 4; ++is) {
      int s = is * 256 + t;
      int row = s >> 3, pos = s & 7;
      int kc = pos ^ (row & 7);
      gload_lds16(A + (size_t)(m0 + row) * NEMBD + k0 + kc * 8, &As[s * 8]);
      gload_lds16(B + (size_t)(n0 + row) * NEMBD + k0 + kc * 8, &Bs[s * 8]);
    }
    __syncthreads();
#pragma unroll
    for (int kh = 0; kh < 2; ++kh) {
      short8 af[4], bfr[4];
#pragma unroll
      for (int mt = 0; mt < 4; ++mt) {
        int row = wm * 64 + mt * 16 + l15;
        af[mt] = *(const short8*)&As[row * 64 + (((kh * 4 + quad) ^ (row & 7)) * 8)];
      }
#pragma unroll
      for (int nt = 0; nt < 4; ++nt) {
        int row = wn * 64 + nt * 16 + l15;
        bfr[nt] = *(const short8*)&Bs[row * 64 + (((kh * 4 + quad) ^ (row & 7)) * 8)];
      }
      if (is_v) {
#pragma unroll
        for (int mt = 0; mt < 4; ++mt)
#pragma unroll
          for (int nt = 0; nt < 4; ++nt)
            acc[mt][nt] = MFMA16(af[mt], bfr[nt], acc[mt][nt]);   // D[m][n]
      } else {
#pragma unroll
        for (int mt = 0; mt < 4; ++mt)
#pragma unroll
          for (int nt = 0; nt < 4; ++nt)
            acc[mt][nt] = MFMA16(bfr[nt], af[mt], acc[mt][nt]);   // D[n][m]
      }
    }
  }

  if (is_v) {
    // D rows = tokens (quad*4+r), cols = hd (l15): pack 4 tokens -> vtg[hd][token]
#pragma unroll
    for (int mt = 0; mt < 4; ++mt)
#pragma unroll
      for (int nt = 0; nt < 4; ++nt) {
        int hd = n0 + wn * 64 + nt * 16 + l15 - 2 * NEMBD;
        int token = m0 + wm * 64 + mt * 16 + quad * 4;
        int b = token >> 11, tp = token & (SEQ - 1);
        ushort4v pk;
#pragma unroll
        for (int r = 0; r < 4; ++r) pk[r] = f2bf(acc[mt][nt][r]);
        *(ushort4v*)&vtg[((size_t)(b * NEMBD + hd)) * SEQ + tp] = pk;
      }
  } else {
    // swapped: D rows = n (quad*4+r), cols = token (l15): pack 4 n -> qkb[token][n]
#pragma unroll
    for (int mt = 0; mt < 4; ++mt) {
      size_t token = (size_t)(m0 + wm * 64 + mt * 16 + l15);
#pragma unroll
      for (int nt = 0; nt < 4; ++nt) {
        int nc = n0 + wn * 64 + nt * 16 + quad * 4;
        ushort4v pk;
#pragma unroll
        for (int r = 0; r < 4; ++r) pk[r] = f2bf(acc[mt][nt][r]);
        *(ushort4v*)&qkb[token * 2048 + nc] = pk;
      }
    }
  }
}

// ---------------------------------------------------------------------------
// Flash attention (causal), S^T form, fixed-C softmax (C=8), 2-way split-K.
// (unchanged from R4)
// ---------------------------------------------------------------------------
__global__ __launch_bounds__(256) void attn_mfma3(const u16* __restrict__ qkb,
                                                  const u16* __restrict__ vtg,
                                                  u16* __restrict__ opart,
                                                  float* __restrict__ lpart) {
  const int bx = blockIdx.x;
  const int qt = 15 - (bx >> 6);
  const int r6 = bx & 63;
  const int bh = r6 >> 1, half = r6 & 1;
  const int b = bh >> 4, h = bh & 15;
  const int t = threadIdx.x, lane = t & 63, w = t >> 6;
  const int l15 = lane & 15, quad = lane >> 4;

  __shared__ __align__(16) u16 Qs[128 * 64];
  __shared__ __align__(16) u16 Ks[64 * 64];
  __shared__ __align__(16) u16 Vt[64 * 64];
  __shared__ __align__(16) u16 Pa[128 * 72];

  {
    const u16* qb = qkb + ((size_t)(b * SEQ + qt * 128)) * 2048 + h * HDIM;
#pragma unroll
    for (int is = 0; is < 4; ++is) {
      int s = is * 256 + t;
      int row = s >> 3, pos = s & 7;
      int kc = pos ^ (row & 7);
      gload_lds16(qb + (size_t)row * 2048 + kc * 8, &Qs[s * 8]);
    }
  }
  __syncthreads();
  short8 qf[2][2];
#pragma unroll
  for (int qs = 0; qs < 2; ++qs) {
    int qrow = w * 32 + qs * 16 + l15;
#pragma unroll
    for (int hf = 0; hf < 2; ++hf)
      qf[qs][hf] = *(const short8*)&Qs[qrow * 64 + (((hf * 4 + quad) ^ (qrow & 7)) * 8)];
  }

  float rs[2] = {0.f, 0.f};
  floatx4 o_acc[2][4] = {};

  const int kt0 = half ? (qt + 1) : 0;
  const int kt_end = kt0 + qt + 1;
  const int um_end = (kt_end < 2 * qt) ? kt_end : (2 * qt);

#define ATTN_TILE(KT, MASKED)                                                  \
  {                                                                            \
    __syncthreads();                                                           \
    const u16* kb = qkb + ((size_t)(b * SEQ + (KT) * 64)) * 2048 + NEMBD + h * HDIM; \
    const u16* vb = vtg + ((size_t)(bh * 64)) * SEQ + (KT) * 64;               \
    _Pragma("unroll")                                                          \
    for (int is = 0; is < 2; ++is) {                                           \
      int s = is * 256 + t;                                                    \
      int row = s >> 3, pos = s & 7;                                           \
      int kc = pos ^ (row & 7);                                                \
      gload_lds16(kb + (size_t)row * 2048 + kc * 8, &Ks[s * 8]);               \
      gload_lds16(vb + (size_t)row * SEQ + kc * 8, &Vt[s * 8]);                \
    }                                                                          \
    __syncthreads();                                                           \
    floatx4 sacc[2][4];                                                        \
    _Pragma("unroll")                                                          \
    for (int nt = 0; nt < 4; ++nt) {                                           \
      int krow = nt * 16 + l15;                                                \
      short8 kf0 = *(const short8*)&Ks[krow * 64 + ((quad ^ (krow & 7)) * 8)]; \
      short8 kf1 = *(const short8*)&Ks[krow * 64 + (((4 + quad) ^ (krow & 7)) * 8)]; \
      _Pragma("unroll")                                                        \
      for (int qs = 0; qs < 2; ++qs) {                                         \
        floatx4 z = {0.f, 0.f, 0.f, 0.f};                                      \
        z = MFMA16(kf0, qf[qs][0], z);                                         \
        z = MFMA16(kf1, qf[qs][1], z);                                         \
        sacc[qs][nt] = z;                                                      \
      }                                                                        \
    }                                                                          \
    _Pragma("unroll")                                                          \
    for (int qs = 0; qs < 2; ++qs) {                                           \
      const int qg = qt * 128 + w * 32 + qs * 16 + l15;                        \
      const int kb0 = (KT) * 64 + quad * 4;                                    \
      _Pragma("unroll")                                                        \
      for (int nt = 0; nt < 4; ++nt) {                                         \
        ushort4v pk;                                                           \
        _Pragma("unroll")                                                      \
        for (int r = 0; r < 4; ++r) {                                          \
          float p = exp2f(fmaf(sacc[qs][nt][r], SCALE_LOG2E, -8.0f));          \
          if (MASKED && (kb0 + nt * 16 + r) > qg) p = 0.0f;                    \
          rs[qs] += p;                                                         \
          pk[r] = f2bf(p);                                                     \
        }                                                                      \
        *(ushort4v*)&Pa[(w * 32 + qs * 16 + l15) * 72 + nt * 16 + quad * 4] = pk; \
      }                                                                        \
    }                                                                          \
    short8 pf[2][2];                                                           \
    _Pragma("unroll")                                                          \
    for (int qs = 0; qs < 2; ++qs) {                                           \
      const int prow = w * 32 + qs * 16 + l15;                                 \
      pf[qs][0] = *(const short8*)&Pa[prow * 72 + quad * 8];                   \
      pf[qs][1] = *(const short8*)&Pa[prow * 72 + 32 + quad * 8];              \
    }                                                                          \
    _Pragma("unroll")                                                          \
    for (int nt = 0; nt < 4; ++nt) {                                           \
      int drow = nt * 16 + l15;                                                \
      short8 vf0 = *(const short8*)&Vt[drow * 64 + ((quad ^ (drow & 7)) * 8)]; \
      short8 vf1 = *(const short8*)&Vt[drow * 64 + (((4 + quad) ^ (drow & 7)) * 8)]; \
      _Pragma("unroll")                                                        \
      for (int qs = 0; qs < 2; ++qs) {                                         \
        o_acc[qs][nt] = MFMA16(pf[qs][0], vf0, o_acc[qs][nt]);                 \
        o_acc[qs][nt] = MFMA16(pf[qs][1], vf1, o_acc[qs][nt]);                 \
      }                                                                        \
    }                                                                          \
  }

  int kt = kt0;
  for (; kt < um_end; ++kt) ATTN_TILE(kt, 0);
  for (; kt < kt_end; ++kt) ATTN_TILE(kt, 1);
#undef ATTN_TILE

#pragma unroll
  for (int qs = 0; qs < 2; ++qs) {
    rs[qs] += __shfl_xor(rs[qs], 16, 64);
    rs[qs] += __shfl_xor(rs[qs], 32, 64);
    if (quad == 0)
      lpart[((size_t)half * 32 + bh) * SEQ + qt * 128 + w * 32 + qs * 16 + l15] = rs[qs];
  }
  u16* ob = opart + (size_t)half * BT * NEMBD;
#pragma unroll
  for (int qs = 0; qs < 2; ++qs)
#pragma unroll
    for (int nt = 0; nt < 4; ++nt)
#pragma unroll
      for (int r = 0; r < 4; ++r) {
        size_t tok = (size_t)(b * SEQ + qt * 128 + w * 32 + qs * 16 + quad * 4 + r);
        ob[tok * NEMBD + h * HDIM + nt * 16 + l15] = f2bf(o_acc[qs][nt][r]);
      }
}

// ---------------------------------------------------------------------------
__global__ __launch_bounds__(256) void combine(const u16* __restrict__ opart,
                                               const float* __restrict__ lpart,
                                               u16* __restrict__ yb) {
  int idx = (blockIdx.x * 256 + threadIdx.x) * 4;
  int tok = idx >> 10, c = idx & 1023;
  int b = tok >> 11, q = tok & (SEQ - 1), h = c >> 6;
  float l = lpart[(size_t)(b * 16 + h) * SEQ + q] +
            lpart[(size_t)(32 + b * 16 + h) * SEQ + q];
  float inv = 1.0f / l;
  ushort4v o0 = *(const ushort4v*)&opart[idx];
  ushort4v o1 = *(const ushort4v*)&opart[(size_t)BT * NEMBD + idx];
  ushort4v yo;
#pragma unroll
  for (int j = 0; j < 4; ++j) {
    float f0 = __builtin_bit_cast(float, (unsigned)o0[j] << 16);
    float f1 = __builtin_bit_cast(float, (unsigned)o1[j] << 16);
    yo[j] = f2bf((f0 + f1) * inv);
  }
  *(ushort4v*)&yb[idx] = yo;
}

// ---------------------------------------------------------------------------
// GEMM2: out(fp32) = yb @ w_proj^T. 128x64 tile, BK=64 swizzled,
// operand-swapped -> float4 stores. 512 blocks.
// ---------------------------------------------------------------------------
__global__ __launch_bounds__(256) void gemm_out(const u16* __restrict__ A,
                                                const u16* __restrict__ B,
                                                float* __restrict__ C) {
  __shared__ __align__(16) u16 As[128 * 64];  // 16 KB
  __shared__ __align__(16) u16 Bs[64 * 64];   //  8 KB
  const int t = threadIdx.x;
  const int lane = t & 63, w = t >> 6;
  const int l15 = lane & 15, quad = lane >> 4;
  const int wm = w >> 1, wn = w & 1;
  const int m0 = blockIdx.y * 128, n0 = blockIdx.x * 64;

  floatx4 acc[4][2] = {};

  for (int k0 = 0; k0 < NEMBD; k0 += 64) {
    __syncthreads();
#pragma unroll
    for (int is = 0; is < 4; ++is) {
      int s = is * 256 + t;
      int row = s >> 3, pos = s & 7;
      int kc = pos ^ (row & 7);
      gload_lds16(A + (size_t)(m0 + row) * NEMBD + k0 + kc * 8, &As[s * 8]);
    }
#pragma unroll
    for (int is = 0; is < 2; ++is) {
      int s = is * 256 + t;
      int row = s >> 3, pos = s & 7;
      int kc = pos ^ (row & 7);
      gload_lds16(B + (size_t)(n0 + row) * NEMBD + k0 + kc * 8, &Bs[s * 8]);
    }
    __syncthreads();
#pragma unroll
    for (int kh = 0; kh < 2; ++kh) {
      short8 af[4], bfr[2];
#pragma unroll
      for (int mt = 0; mt < 4; ++mt) {
        int row = wm * 64 + mt * 16 + l15;
        af[mt] = *(const short8*)&As[row * 64 + (((kh * 4 + quad) ^ (row & 7)) * 8)];
      }
#pragma unroll
      for (int nt = 0; nt < 2; ++nt) {
        int row = wn * 32 + nt * 16 + l15;
        bfr[nt] = *(const short8*)&Bs[row * 64 + (((kh * 4 + quad) ^ (row & 7)) * 8)];
      }
#pragma unroll
      for (int mt = 0; mt < 4; ++mt)
#pragma unroll
        for (int nt = 0; nt < 2; ++nt)
          acc[mt][nt] = MFMA16(bfr[nt], af[mt], acc[mt][nt]);   // D[n][m]
    }
  }

  // swapped: rows = n (quad*4+r), cols = token (l15) -> float4 stores
#pragma unroll
  for (int mt = 0; mt < 4; ++mt) {
    size_t token = (size_t)(m0 + wm * 64 + mt * 16 + l15);
#pragma unroll
    for (int nt = 0; nt < 2; ++nt) {
      int nc = n0 + wn * 32 + nt * 16 + quad * 4;
      float4 v = make_float4(acc[mt][nt][0], acc[mt][nt][1],
                             acc[mt][nt][2], acc[mt][nt][3]);
      *(float4*)&C[token * NEMBD + nc] = v;
    }
  }
}

// ---------------------------------------------------------------------------
extern "C" void kernel_launch(void* const* d_in, const int* in_sizes, int n_in,
                              void* d_out, int out_size, void* d_ws, size_t ws_size,
                              hipStream_t stream) {
  const float* x      = (const float*)d_in[0];
  const float* w_attn = (const float*)d_in[1];
  const float* w_proj = (const float*)d_in[2];
  float* out = (float*)d_out;

  // Workspace (u16 units). opart ALIASES xb+wab (dead after gemm_qkv).
  u16* base  = (u16*)d_ws;
  u16* opart = base;                       // 2*4096*1024 u16 = 16 MB
  u16* xb    = base;                       // alias
  u16* wab   = base + 4194304;             // alias
  u16* wpb   = base + 8388608;             // 2 MB
  u16* qkb   = base + 9437184;             // 16 MB
  u16* vtg   = base + 17825792;            // 8 MB
  u16* yb    = base + 22020096;            // 8 MB
  float* lpart = (float*)(base + 26214400);  // 0.5 MB

  cvt_all<<<(N_X + N_WA + N_WP) / 2048, 256, 0, stream>>>(x, w_attn, w_proj, xb, wab, wpb);

  gemm_qkv<<<dim3(QKV_LD / 128, BT / 128), 256, 0, stream>>>(xb, wab, qkb, vtg);

  attn_mfma3<<<dim3((SEQ / 128) * BSZ * NHEAD * 2), 256, 0, stream>>>(qkb, vtg, opart, lpart);

  combine<<<(BT * NEMBD) / 1024, 256, 0, stream>>>(opart, lpart, yb);

  gemm_out<<<dim3(NEMBD / 64, BT / 128), 256, 0, stream>>>(yb, wpb, out);
}